// Round 1
// baseline (639.074 us; speedup 1.0000x reference)
//
#include <hip/hip_runtime.h>

#define OUTF 64

__device__ __forceinline__ float bcast_lane(float v, int k) {
    return __int_as_float(__builtin_amdgcn_readlane(__float_as_int(v), k));
}

__global__ __launch_bounds__(256, 4)
void gcmc_edge(const float* __restrict__ weight,
               const float* __restrict__ prob_w,
               const float* __restrict__ rscore_w,
               const float* __restrict__ review_w,
               const float* __restrict__ feat,
               const float* __restrict__ cj,
               const float* __restrict__ ci,
               const int* __restrict__ src_idx,
               const int* __restrict__ dst_idx,
               float* __restrict__ out,
               int E)
{
    const int lane = threadIdx.x & 63;
    const int wid  = blockIdx.x * (blockDim.x >> 6) + (threadIdx.x >> 6);
    const int nw   = gridDim.x * (blockDim.x >> 6);

    // Lane o holds review_w row o in registers: rw[k] = review_w[o][k]
    float rw[64];
#pragma unroll
    for (int j = 0; j < 16; ++j) {
        const float4 v = reinterpret_cast<const float4*>(review_w)[lane * 16 + j];
        rw[4 * j + 0] = v.x;
        rw[4 * j + 1] = v.y;
        rw[4 * j + 2] = v.z;
        rw[4 * j + 3] = v.w;
    }
    const float pw = prob_w[lane];
    const float sw = rscore_w[lane];

    for (int e = wid; e < E; e += nw) {
        const float f = feat[(size_t)e * OUTF + lane];

        // gate dot products, wave-reduced
        float px = f * pw;
        float sx = f * sw;
#pragma unroll
        for (int off = 32; off > 0; off >>= 1) {
            px += __shfl_xor(px, off, 64);
            sx += __shfl_xor(sx, off, 64);
        }
        const float pa = __fdividef(1.0f, 1.0f + __expf(-px));
        const float gs = __fdividef(1.0f, 1.0f + __expf(-sx));

        // rf[o] = sum_k feat[k] * review_w[o][k]; feat[k] broadcast via readlane
        float rf0 = 0.0f, rf1 = 0.0f, rf2 = 0.0f, rf3 = 0.0f;
#pragma unroll
        for (int k = 0; k < 16; ++k) {
            rf0 += bcast_lane(f, 4 * k + 0) * rw[4 * k + 0];
            rf1 += bcast_lane(f, 4 * k + 1) * rw[4 * k + 1];
            rf2 += bcast_lane(f, 4 * k + 2) * rw[4 * k + 2];
            rf3 += bcast_lane(f, 4 * k + 3) * rw[4 * k + 3];
        }
        const float rf = ((rf0 + rf1) + (rf2 + rf3)) * gs;

        const int s = src_idx[e];
        const int d = dst_idx[e];
        const float scale = cj[s] * ci[d];   // fold ci into message (distributes over segment_sum)
        const float m = (weight[(size_t)s * OUTF + lane] * pa + rf) * scale;

        unsafeAtomicAdd(&out[(size_t)d * OUTF + lane], m);
    }
}

extern "C" void kernel_launch(void* const* d_in, const int* in_sizes, int n_in,
                              void* d_out, int out_size, void* d_ws, size_t ws_size,
                              hipStream_t stream) {
    const float* weight    = (const float*)d_in[0];
    const float* prob_w    = (const float*)d_in[1];
    const float* rscore_w  = (const float*)d_in[2];
    const float* review_w  = (const float*)d_in[3];
    const float* feat      = (const float*)d_in[4];
    const float* cj        = (const float*)d_in[5];
    const float* ci        = (const float*)d_in[6];
    const int*   src_idx   = (const int*)d_in[7];
    const int*   dst_idx   = (const int*)d_in[8];
    float* out = (float*)d_out;
    const int E = in_sizes[7];

    hipMemsetAsync(d_out, 0, (size_t)out_size * sizeof(float), stream);

    const int block = 256;
    const int grid = 2048;
    gcmc_edge<<<grid, block, 0, stream>>>(weight, prob_w, rscore_w, review_w, feat,
                                          cj, ci, src_idx, dst_idx, out, E);
}

// Round 2
// 415.144 us; speedup vs baseline: 1.5394x; 1.5394x over previous
//
#include <hip/hip_runtime.h>

typedef __attribute__((ext_vector_type(8))) short short8;
typedef __attribute__((ext_vector_type(16))) float f32x16;

union Frag {
    short8 v;
    unsigned u[4];
};

__device__ __forceinline__ unsigned pack_bf16(float lo, float hi) {
    unsigned r;
    asm volatile("v_cvt_pk_bf16_f32 %0, %1, %2" : "=v"(r) : "v"(lo), "v"(hi));
    return r;
}

__global__ __launch_bounds__(256, 2)
void gcmc_edge_mfma(const float* __restrict__ weight,
                    const float* __restrict__ prob_w,
                    const float* __restrict__ rscore_w,
                    const float* __restrict__ review_w,
                    const float* __restrict__ feat,
                    const float* __restrict__ cj,
                    const float* __restrict__ ci,
                    const int* __restrict__ src_idx,
                    const int* __restrict__ dst_idx,
                    float* __restrict__ out,
                    int E)
{
    const int lane = threadIdx.x & 63;
    const int h = lane >> 5;        // k-half
    const int c = lane & 31;        // row (A) / col (B, C/D)
    const int wid = blockIdx.x * (blockDim.x >> 6) + (threadIdx.x >> 6);
    const int nw = gridDim.x * (blockDim.x >> 6);

    const float4* rw4 = reinterpret_cast<const float4*>(review_w);
    const float4* pw4 = reinterpret_cast<const float4*>(prob_w);
    const float4* sw4 = reinterpret_cast<const float4*>(rscore_w);
    const float4* ft4 = reinterpret_cast<const float4*>(feat);

    // B fragments: B[k][o] = review_w[o][k]; lane holds col o = 32t+c,
    // k = 16s + 8h + j (j=0..7). Loaded once, kept in registers (bf16).
    Frag bf[2][4];
#pragma unroll
    for (int t = 0; t < 2; ++t) {
#pragma unroll
        for (int s = 0; s < 4; ++s) {
            const float4 r0 = rw4[(32 * t + c) * 16 + 4 * s + 2 * h];
            const float4 r1 = rw4[(32 * t + c) * 16 + 4 * s + 2 * h + 1];
            bf[t][s].u[0] = pack_bf16(r0.x, r0.y);
            bf[t][s].u[1] = pack_bf16(r0.z, r0.w);
            bf[t][s].u[2] = pack_bf16(r1.x, r1.y);
            bf[t][s].u[3] = pack_bf16(r1.z, r1.w);
        }
    }

    const int nbatch = E >> 5;  // full 32-edge batches

    for (int b = wid; b < nbatch; b += nw) {
        const int e0 = b << 5;

        // ---- A fragments (feat rows) + f32 gate partial dots ----
        Frag af[4];
        float px = 0.0f, sx = 0.0f;
#pragma unroll
        for (int s = 0; s < 4; ++s) {
            const size_t base = (size_t)(e0 + c) * 16 + 4 * s + 2 * h;
            const float4 f0 = ft4[base];
            const float4 f1 = ft4[base + 1];
            const float4 p0 = pw4[4 * s + 2 * h];
            const float4 p1 = pw4[4 * s + 2 * h + 1];
            const float4 q0 = sw4[4 * s + 2 * h];
            const float4 q1 = sw4[4 * s + 2 * h + 1];
            px += f0.x * p0.x + f0.y * p0.y + f0.z * p0.z + f0.w * p0.w
                + f1.x * p1.x + f1.y * p1.y + f1.z * p1.z + f1.w * p1.w;
            sx += f0.x * q0.x + f0.y * q0.y + f0.z * q0.z + f0.w * q0.w
                + f1.x * q1.x + f1.y * q1.y + f1.z * q1.z + f1.w * q1.w;
            af[s].u[0] = pack_bf16(f0.x, f0.y);
            af[s].u[1] = pack_bf16(f0.z, f0.w);
            af[s].u[2] = pack_bf16(f1.x, f1.y);
            af[s].u[3] = pack_bf16(f1.z, f1.w);
        }

        // ---- finish gates: sum the two k-halves, sigmoid ----
        px += __shfl_xor(px, 32, 64);
        sx += __shfl_xor(sx, 32, 64);
        const float pa = __fdividef(1.0f, 1.0f + __expf(-px));
        const float gs = __fdividef(1.0f, 1.0f + __expf(-sx));

        // per-edge scalars live at lane (e&31) in both halves
        const int se = src_idx[e0 + c];
        const int de = dst_idx[e0 + c];
        const float cjci = cj[se] * ci[de];
        const float Ae = pa * cjci;   // multiplies weight[src]
        const float Be = gs * cjci;   // multiplies rf

        // ---- MFMA: rf_raw[32 edges][64 outs] ----
        f32x16 acc0 = {0.0f};
        f32x16 acc1 = {0.0f};
#pragma unroll
        for (int s = 0; s < 4; ++s) {
            acc0 = __builtin_amdgcn_mfma_f32_32x32x16_bf16(af[s].v, bf[0][s].v, acc0, 0, 0, 0);
            acc1 = __builtin_amdgcn_mfma_f32_32x32x16_bf16(af[s].v, bf[1][s].v, acc1, 0, 0, 0);
        }

        // ---- epilogue: D layout col=c, row e = (r&3)+8*(r>>2)+4h ----
#pragma unroll
        for (int r = 0; r < 16; ++r) {
            const int e_lr = (r & 3) + 8 * (r >> 2) + 4 * h;
            const float Ar = __shfl(Ae, e_lr, 64);
            const float Br = __shfl(Be, e_lr, 64);
            const int sr = __shfl(se, e_lr, 64);
            const int dr = __shfl(de, e_lr, 64);
            const float w0 = weight[sr * 64 + c];
            const float w1 = weight[sr * 64 + 32 + c];
            const float m0 = acc0[r] * Br + w0 * Ar;
            const float m1 = acc1[r] * Br + w1 * Ar;
            unsafeAtomicAdd(&out[dr * 64 + c], m0);
            unsafeAtomicAdd(&out[dr * 64 + 32 + c], m1);
        }
    }

    // ---- scalar fallback for a partial tail batch (E % 32 != 0) ----
    const int tail = nbatch << 5;
    if (tail < E && wid == 0) {
        for (int e = tail; e < E; ++e) {
            float rf = 0.0f, pxs = 0.0f, sxs = 0.0f;
            for (int k = 0; k < 64; ++k) {
                const float f = feat[(size_t)e * 64 + k];
                rf += f * review_w[lane * 64 + k];
                pxs += f * prob_w[k];
                sxs += f * rscore_w[k];
            }
            const float pa = __fdividef(1.0f, 1.0f + __expf(-pxs));
            const float gsv = __fdividef(1.0f, 1.0f + __expf(-sxs));
            const int s_ = src_idx[e];
            const int d_ = dst_idx[e];
            const float sc = cj[s_] * ci[d_];
            const float m = (weight[s_ * 64 + lane] * pa + rf * gsv) * sc;
            unsafeAtomicAdd(&out[d_ * 64 + lane], m);
        }
    }
}

extern "C" void kernel_launch(void* const* d_in, const int* in_sizes, int n_in,
                              void* d_out, int out_size, void* d_ws, size_t ws_size,
                              hipStream_t stream) {
    const float* weight    = (const float*)d_in[0];
    const float* prob_w    = (const float*)d_in[1];
    const float* rscore_w  = (const float*)d_in[2];
    const float* review_w  = (const float*)d_in[3];
    const float* feat      = (const float*)d_in[4];
    const float* cj        = (const float*)d_in[5];
    const float* ci        = (const float*)d_in[6];
    const int*   src_idx   = (const int*)d_in[7];
    const int*   dst_idx   = (const int*)d_in[8];
    float* out = (float*)d_out;
    const int E = in_sizes[7];

    hipMemsetAsync(d_out, 0, (size_t)out_size * sizeof(float), stream);

    const int block = 256;
    const int grid = 1568;   // 6272 waves; 50000 batches -> ~8 per wave, balanced
    gcmc_edge_mfma<<<grid, block, 0, stream>>>(weight, prob_w, rscore_w, review_w, feat,
                                               cj, ci, src_idx, dst_idx, out, E);
}